// Round 8
// baseline (267.748 us; speedup 1.0000x reference)
//
#include <hip/hip_runtime.h>

#define B_ 32
#define C_ 128
#define H_ 56
#define W_ 56
#define HW_ (H_*W_)            // 3136
#define SIZE_ (C_*HW_)         // 401408
#define NPIX_ (B_*HW_)         // 100352 = 1568 * 64
#define HP_ 58
#define WP_ 58
#define PLSZ_ (B_*HP_*WP_*32)  // 3,444,736 ushort per 32-channel chunk plane
#define K_ 1152                // 9 * 128
#define EPS_ 1e-5f
#define SLOPE_ 0.1f

typedef __bf16 bf16x8 __attribute__((ext_vector_type(8)));
typedef float  f32x4  __attribute__((ext_vector_type(4)));

__device__ __forceinline__ ushort f2bf(float x) {
    union { float f; unsigned u; } v; v.f = x;
    return (ushort)((v.u + 0x7FFFu + ((v.u >> 16) & 1u)) >> 16);   // RNE
}
__device__ __forceinline__ float lrelu(float z) { return z > 0.f ? z : SLOPE_ * z; }

// async global->LDS, 16B per lane (used by zfuse staging only)
__device__ __forceinline__ void glds16(const ushort* g, ushort* l) {
    __builtin_amdgcn_global_load_lds(
        (const __attribute__((address_space(1))) unsigned int*)g,
        (__attribute__((address_space(3))) unsigned int*)l, 16, 0, 0);
}

// ---------------------------------------------------------------------------
// prep: repack conv_w -> bf16 wA36[t36][co128][32k]  (K-step t = k/32: each
// step's 128x32 A-slice is one contiguous 8KB block; a lane's dwordx4 frag
// read is fully coalesced and the slice is L1/L2-broadcast to all blocks);
// fold bias+BN2; fold BN1 into per-position mix params p0,p1,p2.
// ---------------------------------------------------------------------------
__global__ __launch_bounds__(256) void prep_kernel(
    const float* __restrict__ conv_w, const float* __restrict__ conv_b,
    const float* __restrict__ g2, const float* __restrict__ b2,
    const float* __restrict__ m2, const float* __restrict__ v2,
    const float2* __restrict__ cfc, const float* __restrict__ g1,
    const float* __restrict__ b1, const float* __restrict__ mu1,
    const float* __restrict__ v1,
    ushort* __restrict__ wA, float* __restrict__ scale2, float* __restrict__ shift2,
    float* __restrict__ p0, float* __restrict__ p1, float* __restrict__ p2)
{
    int tid = blockIdx.x * 256 + threadIdx.x;
    if (tid < C_ * K_) {
        int co = tid / K_;
        int k  = tid - co * K_;           // k = tap*128 + ci = t*32 + kk
        int t  = k >> 5, kk = k & 31;
        int khkw = k >> 7, ci = k & 127;
        int kh = khkw / 3, kw = khkw - 3 * kh;
        wA[(t * C_ + co) * 32 + kk] = f2bf(conv_w[((co * C_ + ci) * 3 + kh) * 3 + kw]);
    }
    if (tid < C_) {
        float sc = g2[tid] * rsqrtf(v2[tid] + EPS_);
        scale2[tid] = sc;
        shift2[tid] = (conv_b[tid] - m2[tid]) * sc + b2[tid];
    }
    if (tid < SIZE_) {
        float sc = g1[tid] * rsqrtf(v1[tid] + EPS_);
        float2 wv = cfc[tid];
        p0[tid] = wv.x * sc;
        p1[tid] = wv.y * sc;
        p2[tid] = b1[tid] - mu1[tid] * sc;
    }
}

// ---------------------------------------------------------------------------
// zfuse: z = leaky(a*p0 + m*p1 + p2) -> bf16, FOUR zero-padded 32-channel
// chunk planes zp2[kc][b][hp][wp][32].  UNCHANGED from R6 (glds16 MLP slab
// staging + XCD-contiguous-hp swizzle).
// ---------------------------------------------------------------------------
__global__ __launch_bounds__(256, 4) void zfuse_kernel(
    const float4* __restrict__ ax, const float4* __restrict__ mx,
    const float4* __restrict__ p0, const float4* __restrict__ p1,
    const float4* __restrict__ p2, ushort* __restrict__ zp)
{
    __shared__ float4 axS[4][448];      // 28672 B: [wave][c_loc*14 + w4]
    __shared__ float4 mxS[4][448];      // 28672 B
    __shared__ ushort tile[W_ * 132];   // 14784 B: stride 132, transposed z

    const int tid = threadIdx.x;
    const int wg  = blockIdx.x;
    const int swz = (wg & 7) * 232 + (wg >> 3);
    const int hp  = swz >> 5;           // hp-major
    const int b   = swz & 31;
    const int rb  = (b * HP_ + hp) * (WP_ * 32);    // row base within a plane

    if (hp == 0 || hp == HP_ - 1) {     // full zero border rows, all 4 planes
        for (int ks = 0; ks < 4; ++ks) {
            uint2* r2 = (uint2*)(zp + ks * PLSZ_ + rb);
            for (int i = tid; i < WP_ * 32 / 4; i += 256) r2[i] = make_uint2(0u, 0u);
        }
        return;
    }
    const int h  = hp - 1;
    const int wv = tid >> 6, l = tid & 63;
    const int base4 = b * (SIZE_ / 4);
    const int hb4   = h * (W_ / 4);     // h*14

    #pragma unroll
    for (int j = 0; j < 7; ++j) {
        int i  = j * 64 + l;            // 448 float4s per slab, exact
        int cl = i / 14, w4 = i - cl * 14;
        int s4 = (wv * 32 + cl) * (HW_ / 4) + hb4 + w4;
        glds16((const ushort*)(ax + base4 + s4), (ushort*)&axS[wv][j * 64]);
        glds16((const ushort*)(mx + base4 + s4), (ushort*)&mxS[wv][j * 64]);
    }
    asm volatile("s_waitcnt vmcnt(0)" ::: "memory");
    __builtin_amdgcn_sched_barrier(0);  // rule 18: no hoist past inline-asm wait

    #pragma unroll
    for (int u = 0; u < 7; ++u) {
        int i  = u * 64 + l;
        int cl = i / 14, w4 = i - cl * 14;
        int c  = wv * 32 + cl;
        int s4 = c * (HW_ / 4) + hb4 + w4;
        float4 a  = axS[wv][i];
        float4 m  = mxS[wv][i];
        float4 q0 = p0[s4], q1 = p1[s4], q2 = p2[s4];
        int wb = w4 * 4;
        tile[(wb + 0) * 132 + c] = f2bf(lrelu(a.x * q0.x + m.x * q1.x + q2.x));
        tile[(wb + 1) * 132 + c] = f2bf(lrelu(a.y * q0.y + m.y * q1.y + q2.y));
        tile[(wb + 2) * 132 + c] = f2bf(lrelu(a.z * q0.z + m.z * q1.z + q2.z));
        tile[(wb + 3) * 132 + c] = f2bf(lrelu(a.w * q0.w + m.w * q1.w + q2.w));
    }
    __syncthreads();

    {   // left/right border columns: 4 planes x 32 ch x 2 sides = 256 threads
        int side = (tid >> 7) & 1, ks = (tid >> 5) & 3, cc = tid & 31;
        zp[ks * PLSZ_ + rb + (side ? (WP_ - 1) * 32 : 0) + cc] = 0;
    }
    for (int j = tid; j < 1792; j += 256) {    // 4 planes * 56 w * 8 uint2-chunks
        int ks = j / 448, r = j - ks * 448;
        int w = r >> 3, cc = r & 7;
        *(uint2*)(zp + ks * PLSZ_ + rb + (w + 1) * 32 + cc * 4) =
            *(const uint2*)(tile + w * 132 + ks * 32 + cc * 4);
    }
}

// ---------------------------------------------------------------------------
// conv v7: implicit GEMM, NO LDS, NO BARRIERS.  1 wave/block, 64co x 64px
// tile, grid 3136 = 1568 px-tiles x 2 co-halves (XCD-swizzled; co-pair
// blocks adjacent -> share B in L2/L1).
// Rationale: all prior variants (5 schedules) pinned at MfmaUtil 16-18% --
// the invariant was 512 B of LDS traffic per MFMA plus wave-coupled barrier
// stalls.  Here both fragment types are PERFECTLY coalescable from global:
//   A-frag: wA36[t][co][32], lane l16->co row, quad->16B chunk = 1KB/load,
//           8KB/step shared by ALL blocks -> L1-broadcast.
//   B-frag: k-chunk plane, lane l16->px (64B apart), quad->chunk = 1KB/load.
// 8 loads + 16 MFMA per K-step, fully unrolled, zero sync instructions;
// compiler pipelines across steps under the 128-VGPR cap -> 16 waves/CU of
// independent dataflow.  Tail: 3136 blocks -> no grid quantization.
// Fragment row/chunk mapping byte-identical to the R3-verified LDS reads.
// ---------------------------------------------------------------------------
__global__ __launch_bounds__(64, 4) void conv_kernel(
    const ushort* __restrict__ zp, const ushort* __restrict__ wA,
    const float* __restrict__ scale2, const float* __restrict__ shift2,
    float* __restrict__ out)
{
    const int lane = threadIdx.x & 63;
    const int l16  = lane & 15, quad = lane >> 4;
    // XCD swizzle: 3136 = 8 x 392; adjacent swz = co-pair of same px tile
    const int bid  = blockIdx.x;
    const int swz  = (bid & 7) * 392 + (bid >> 3);
    const int pbase = (swz >> 1) * 64;
    const int cob   = (swz & 1) * 64;

    // per-lane A pointer: row co = cob + l16 (+mt*512 elems), chunk quad
    const ushort* aptr = wA + (cob + l16) * 32 + quad * 8;

    // per-lane B pointers per nt: px = pbase + nt*16 + l16, chunk quad
    const ushort* bptr[4];
    #pragma unroll
    for (int nt = 0; nt < 4; ++nt) {
        int pf = pbase + nt * 16 + l16;
        int bb = pf / HW_, pi = pf - bb * HW_;
        int h  = pi / W_, w = pi - h * W_;
        bptr[nt] = zp + ((bb * HP_ + h) * WP_ + w) * 32 + quad * 8;
    }

    // B element offset of K-step t: plane (t&3), tap shift (kh*WP+kw)*32
#define BOFF(t) (((t) & 3) * PLSZ_ + (((((t) >> 2) / 3) * WP_ + (((t) >> 2) % 3)) * 32))

    f32x4 acc[4][4] = {};

    #pragma unroll
    for (int t = 0; t < 36; ++t) {
        bf16x8 af[4], bfr[4];
        #pragma unroll
        for (int mt = 0; mt < 4; ++mt)
            af[mt] = *(const bf16x8*)(aptr + t * 4096 + mt * 512);
        #pragma unroll
        for (int nt = 0; nt < 4; ++nt)
            bfr[nt] = *(const bf16x8*)(bptr[nt] + BOFF(t));
        #pragma unroll
        for (int mt = 0; mt < 4; ++mt)
            #pragma unroll
            for (int nt = 0; nt < 4; ++nt)
                acc[mt][nt] = __builtin_amdgcn_mfma_f32_16x16x32_bf16(
                    af[mt], bfr[nt], acc[mt][nt], 0, 0, 0);
    }
#undef BOFF

    // ---- epilogue: fused scale/shift + leaky, NCHW fp32 stores ----
    int pob[4];
    #pragma unroll
    for (int nt = 0; nt < 4; ++nt) {
        int pf = pbase + nt * 16 + l16;
        int bb = pf / HW_;
        pob[nt] = bb * SIZE_ + (pf - bb * HW_);
    }
    #pragma unroll
    for (int mt = 0; mt < 4; ++mt) {
        #pragma unroll
        for (int r = 0; r < 4; ++r) {
            int co = cob + mt * 16 + quad * 4 + r;
            float sc = scale2[co], sh = shift2[co];
            #pragma unroll
            for (int nt = 0; nt < 4; ++nt) {
                float v = acc[mt][nt][r] * sc + sh;
                out[(size_t)pob[nt] + co * HW_] = lrelu(v);
            }
        }
    }
}

// ---------------------------------------------------------------------------
extern "C" void kernel_launch(void* const* d_in, const int* in_sizes, int n_in,
                              void* d_out, int out_size, void* d_ws, size_t ws_size,
                              hipStream_t stream) {
    const float* ax     = (const float*)d_in[0];
    const float* mx     = (const float*)d_in[1];
    const float* cfc    = (const float*)d_in[2];
    const float* bn_g   = (const float*)d_in[3];
    const float* bn_b   = (const float*)d_in[4];
    const float* bn_m   = (const float*)d_in[5];
    const float* bn_v   = (const float*)d_in[6];
    const float* conv_w = (const float*)d_in[7];
    const float* conv_b = (const float*)d_in[8];
    const float* g2     = (const float*)d_in[9];
    const float* b2     = (const float*)d_in[10];
    const float* m2     = (const float*)d_in[11];
    const float* v2     = (const float*)d_in[12];
    float* out = (float*)d_out;

    char* ws = (char*)d_ws;
    // zp2: 4 planes x 6,889,472 B = 27,557,888 B | wA36: 294,912 B | scale2/shift2 | p0/p1/p2
    ushort* zp     = (ushort*)ws;
    ushort* wA     = (ushort*)(ws + 27557888);
    float*  scale2 = (float*)(ws + 27852800);
    float*  shift2 = (float*)(ws + 27853312);
    float*  p0     = (float*)(ws + 27853824);
    float*  p1     = (float*)(ws + 29459456);
    float*  p2     = (float*)(ws + 31065088);

    prep_kernel<<<dim3((SIZE_ + 255) / 256), 256, 0, stream>>>(
        conv_w, conv_b, g2, b2, m2, v2, (const float2*)cfc,
        bn_g, bn_b, bn_m, bn_v, wA, scale2, shift2, p0, p1, p2);
    zfuse_kernel<<<dim3(HP_ * B_), 256, 0, stream>>>(
        (const float4*)ax, (const float4*)mx,
        (const float4*)p0, (const float4*)p1, (const float4*)p2, zp);
    conv_kernel<<<dim3(NPIX_ / 64 * 2), 64, 0, stream>>>(zp, wA, scale2, shift2, out);
}